// Round 24
// baseline (108.296 us; speedup 1.0000x reference)
//
#include <hip/hip_runtime.h>
#include <hip/hip_bf16.h>
#include <hip/hip_fp16.h>
#include <math.h>

#define NN 1024
#define CC 128
#define C2 64
#define KK 16
#define NCAND 24

#if __has_builtin(__builtin_amdgcn_exp2f)
#define EXP2F(x) __builtin_amdgcn_exp2f(x)
#else
#define EXP2F(x) exp2f(x)
#endif
#define LOG2E 1.4426950408889634f

typedef __fp16  hf2   __attribute__((ext_vector_type(2)));   // cvt_pkrtz result type
typedef _Float16 half8 __attribute__((ext_vector_type(8)));  // MFMA operand type
typedef float f32x4    __attribute__((ext_vector_type(4)));
typedef int   int4v    __attribute__((ext_vector_type(4)));
typedef unsigned int uint;

__device__ __forceinline__ float fast_rcp(float x) {
    return __builtin_amdgcn_rcpf(x);
}

// In-wave LDS write->read visibility: wait LDS ops, pin compiler order.
#define LDS_FENCE() do { \
    asm volatile("s_waitcnt lgkmcnt(0)" ::: "memory"); \
    __builtin_amdgcn_sched_barrier(0); } while (0)

// ---------------- K1: proj (np-exact) + psE, fused with buildA -------------
// blocks [0, 2*NN): proj; blocks [2*NN, 2*NN+32): A = M^T M.
__global__ __launch_bounds__(128) void proj_buildA(
        const float* __restrict__ X,
        const float* __restrict__ Wm,
        const float* __restrict__ Ws,
        const float* __restrict__ M,
        float* __restrict__ pm,
        float* __restrict__ ps,
        float* __restrict__ psE,
        float* __restrict__ A) {
    if (blockIdx.x >= 2 * NN) {          // ---- buildA: 32 blocks x 128 thr
        const int e = (blockIdx.x - 2 * NN) * 128 + threadIdx.x;  // < 4096
        const int c = e >> 6, d = e & 63;
        float acc = 0.f;
        #pragma unroll 8
        for (int r = 0; r < C2; ++r)
            acc = fmaf(M[r * C2 + c], M[r * C2 + d], acc);
        A[e] = acc;                      // A[c][d] row-major
        return;
    }

    const int bn = blockIdx.x;           // b*1024 + n
    const int b  = bn >> 10;
    const int n  = bn & (NN - 1);
    const int t  = threadIdx.x;          // 0..127

    __shared__ float xv[CC];
    xv[t] = X[b * CC * NN + t * NN + n];
    __syncthreads();

    const int d = t & (C2 - 1);
    const float* wr = ((t < C2) ? Wm : Ws) + d * CC;
    float acc = 0.f;
    #pragma unroll
    for (int c = 0; c < CC; ++c)
        acc = fmaf(wr[c], xv[c], acc);   // sequential k-order, single acc

    float a = __fadd_rn(fabsf(acc), 1e-10f);
    float l = logf(a);
    float r = (acc > 0.f) ? l : ((acc < 0.f) ? -l : 0.f);
    if (t < C2) {
        pm[bn * C2 + d] = r;
    } else {
        ps[bn * C2 + d] = r;
        psE[bn * C2 + d] = EXP2F(r * LOG2E);   // e^ps (proxy pass only)
    }
}

// f32 sigmoid -> packed fp16 B-fragment (single term; proxy only).
#define SIGF16(PMEF, Y0, Y1, BF) do {                                         \
    float s0 = PMEF[0] * fast_rcp(PMEF[0] + (Y0).x);                          \
    float s1 = PMEF[1] * fast_rcp(PMEF[1] + (Y0).y);                          \
    float s2 = PMEF[2] * fast_rcp(PMEF[2] + (Y0).z);                          \
    float s3 = PMEF[3] * fast_rcp(PMEF[3] + (Y0).w);                          \
    float s4 = PMEF[4] * fast_rcp(PMEF[4] + (Y1).x);                          \
    float s5 = PMEF[5] * fast_rcp(PMEF[5] + (Y1).y);                          \
    float s6 = PMEF[6] * fast_rcp(PMEF[6] + (Y1).z);                          \
    float s7 = PMEF[7] * fast_rcp(PMEF[7] + (Y1).w);                          \
    hf2 p0 = __builtin_amdgcn_cvt_pkrtz(s0, s1);                              \
    hf2 p1 = __builtin_amdgcn_cvt_pkrtz(s2, s3);                              \
    hf2 p2 = __builtin_amdgcn_cvt_pkrtz(s4, s5);                              \
    hf2 p3 = __builtin_amdgcn_cvt_pkrtz(s6, s7);                              \
    int4v iv = { __builtin_bit_cast(int, p0), __builtin_bit_cast(int, p1),    \
                 __builtin_bit_cast(int, p2), __builtin_bit_cast(int, p3) };  \
    BF = __builtin_bit_cast(half8, iv);                                       \
} while (0)

// SINGLE-term fp16 A: 4 MFMA per kt-fragment.
#define MFMA4(AC, KT, B)                                                              \
    AC[0] = __builtin_amdgcn_mfma_f32_16x16x32_f16(af[0][KT], B, AC[0], 0, 0, 0);     \
    AC[1] = __builtin_amdgcn_mfma_f32_16x16x32_f16(af[1][KT], B, AC[1], 0, 0, 0);     \
    AC[2] = __builtin_amdgcn_mfma_f32_16x16x32_f16(af[2][KT], B, AC[2], 0, 0, 0);     \
    AC[3] = __builtin_amdgcn_mfma_f32_16x16x32_f16(af[3][KT], B, AC[3], 0, 0, 0);

// One stream: build 2 fp16 B-fragments, 8 MFMA
#define STREAM(PMEF, T0, T1, T2, T3, AC) do {                                 \
    half8 b0, b1;                                                             \
    SIGF16(PMEF[0], T0, T1, b0);                                              \
    SIGF16(PMEF[1], T2, T3, b1);                                              \
    MFMA4(AC, 0, b0)                                                          \
    MFMA4(AC, 1, b1)                                                          \
} while (0)

#define SQUARE16(AC, S) do {                                                  \
    _Pragma("unroll")                                                         \
    for (int e = 0; e < 4; ++e) {                                             \
        S = fmaf(AC[0][e], AC[0][e], S);                                      \
        S = fmaf(AC[1][e], AC[1][e], S);                                      \
        S = fmaf(AC[2][e], AC[2][e], S);                                      \
        S = fmaf(AC[3][e], AC[3][e], S);                                      \
    }                                                                         \
} while (0)

// ---------------- K2: 4 rows x 8 waves, 512 blocks --------------------------
// Wave wv8 = (hf = wv8>>2, qt = wv8&3).
// launch_bounds (512,2): VGPR cap 256 >= natural ~130 -> NO SPILL (R23's
// (512,4) forced a 64-reg target -> 4.3 MB spill writes, occupancy win erased;
// same trap as R7/R11). Residency: VGPR~130 + LDS 21 KB -> 2 blocks/CU
// -> 4 waves/SIMD achieved WITHOUT a forced cap.
// Phase A: wave covers rows {rbase+hf*2, +1} x tiles [qt*16, +16).
// Phase B: top-NCAND on row (wv8&3) (pairs redundant, deterministic).
// Phase C: wave rescores candidates [hf*12, +12) of row (wv8&3), np-exact.
// F: hf==0 waves write top-16 (desc diff, asc index).
__global__ __launch_bounds__(512, 2) void pair_topk(
        const float* __restrict__ pm,
        const float* __restrict__ ps,
        const float* __restrict__ psE,
        const float* __restrict__ Mf,
        const float* __restrict__ A,
        float* __restrict__ out) {
    const int tid  = threadIdx.x;
    const int wv8  = tid >> 6;           // 0..7
    const int lane = tid & 63;
    const int g    = lane >> 4;          // k-group 0..3
    const int lj   = lane & 15;          // col (B) / row (A) within tile
    const int hf   = wv8 >> 2;           // row-pair (A) / candidate-half (C)
    const int qt   = wv8 & 3;            // tile-quarter (A) / row (B,C,F)

    const int rbase = blockIdx.x * 4;    // first row of block (b-uniform)
    const int b     = rbase >> 10;

    __shared__ uint  d2u[4][NN];         // packed (d2 & ~0x3FF) | j  (16 KB)
    __shared__ float sC[8][2][C2];       // 4 KB
    __shared__ float cdiffL[4][NCAND];

    const float* psb  = ps  + b * NN * C2;
    const float* psEb = psE + b * NN * C2;

    // ---- Phase A: rows r0,r0+1 over tiles [qt*16, +16) ----
    {
        const int r0 = rbase + hf * 2;

        float pmEf0[2][8], pmEf1[2][8];
        #pragma unroll
        for (int kt = 0; kt < 2; ++kt) {
            const float4 a0 = *(const float4*)(pm + r0 * C2 + kt * 32 + g * 8);
            const float4 a1 = *(const float4*)(pm + r0 * C2 + kt * 32 + g * 8 + 4);
            pmEf0[kt][0] = EXP2F(a0.x * LOG2E); pmEf0[kt][1] = EXP2F(a0.y * LOG2E);
            pmEf0[kt][2] = EXP2F(a0.z * LOG2E); pmEf0[kt][3] = EXP2F(a0.w * LOG2E);
            pmEf0[kt][4] = EXP2F(a1.x * LOG2E); pmEf0[kt][5] = EXP2F(a1.y * LOG2E);
            pmEf0[kt][6] = EXP2F(a1.z * LOG2E); pmEf0[kt][7] = EXP2F(a1.w * LOG2E);
            const float4 c0 = *(const float4*)(pm + (r0 + 1) * C2 + kt * 32 + g * 8);
            const float4 c1 = *(const float4*)(pm + (r0 + 1) * C2 + kt * 32 + g * 8 + 4);
            pmEf1[kt][0] = EXP2F(c0.x * LOG2E); pmEf1[kt][1] = EXP2F(c0.y * LOG2E);
            pmEf1[kt][2] = EXP2F(c0.z * LOG2E); pmEf1[kt][3] = EXP2F(c0.w * LOG2E);
            pmEf1[kt][4] = EXP2F(c1.x * LOG2E); pmEf1[kt][5] = EXP2F(c1.y * LOG2E);
            pmEf1[kt][6] = EXP2F(c1.z * LOG2E); pmEf1[kt][7] = EXP2F(c1.w * LOG2E);
        }

        half8 af[4][2];                  // M rows single fp16 (RNE, once)
        #pragma unroll
        for (int rt = 0; rt < 4; ++rt) {
            #pragma unroll
            for (int kt = 0; kt < 2; ++kt) {
                const float* mrow = Mf + (rt * 16 + lj) * C2 + kt * 32 + g * 8;
                const float4 m0 = *(const float4*)mrow;
                const float4 m1 = *(const float4*)(mrow + 4);
                float mv[8] = {m0.x, m0.y, m0.z, m0.w, m1.x, m1.y, m1.z, m1.w};
                #pragma unroll
                for (int e = 0; e < 8; ++e)
                    af[rt][kt][e] = (_Float16)mv[e];        // RNE f32->f16
            }
        }

        const int tbase = qt * 16;       // this wave's 16 tiles

        #pragma unroll 1
        for (int it = 0; it < 16; ++it) {
            const float* pj = psEb + (long)((tbase + it) * 16 + lj) * C2 + g * 8;
            const float4 c0 = *(const float4*)(pj);
            const float4 c1 = *(const float4*)(pj + 4);
            const float4 c2 = *(const float4*)(pj + 32);
            const float4 c3 = *(const float4*)(pj + 36);

            f32x4 ac0[4] = {{0,0,0,0},{0,0,0,0},{0,0,0,0},{0,0,0,0}};
            f32x4 ac1[4] = {{0,0,0,0},{0,0,0,0},{0,0,0,0},{0,0,0,0}};

            __builtin_amdgcn_s_setprio(1);
            STREAM(pmEf0, c0, c1, c2, c3, ac0);
            STREAM(pmEf1, c0, c1, c2, c3, ac1);
            __builtin_amdgcn_s_setprio(0);

            float s0 = 0.f, s1 = 0.f;
            SQUARE16(ac0, s0);
            SQUARE16(ac1, s1);
            s0 += __shfl_xor(s0, 16, 64); s0 += __shfl_xor(s0, 32, 64);
            s1 += __shfl_xor(s1, 16, 64); s1 += __shfl_xor(s1, 32, 64);
            if (lane < 16) {
                const int jj = (tbase + it) * 16 + lane;
                d2u[hf * 2 + 0][jj] = (__float_as_uint(s0) & 0xFFFFFC00u) | (uint)jj;
                d2u[hf * 2 + 1][jj] = (__float_as_uint(s1) & 0xFFFFFC00u) | (uint)jj;
            }
        }
    }
    __syncthreads();

    // ---- Phases B/C: wave handles row rbase+qt; C-half = hf ----
    const int bi = rbase + qt;
    const int i  = bi & (NN - 1);
    const float pm_own = pm[bi * C2 + lane];

    // Phase B: top-NCAND via packed-uint min passes (pairs redundant)
    uint v[16];
    #pragma unroll
    for (int q = 0; q < 16; ++q) v[q] = d2u[qt][q * 64 + lane];

    int myCand = 0;
    #pragma unroll 1
    for (int k = 0; k < NCAND; ++k) {
        uint bv = v[0];
        #pragma unroll
        for (int q = 1; q < 16; ++q) bv = min(bv, v[q]);
        #pragma unroll
        for (int st = 0; st < 6; ++st)
            bv = min(bv, (uint)__shfl_xor((int)bv, 1 << st, 64));
        #pragma unroll
        for (int q = 0; q < 16; ++q)
            if (v[q] == bv) v[q] = 0xFFFFFFFFu;
        if (lane == k) myCand = (int)(bv & 0x3FFu);
    }

    // Phase C: np-exact rescore (R6 bit-exact op order per candidate),
    // this wave: candidates [hf*12, +12), 2 in flight.
    float Acol[C2];
    #pragma unroll
    for (int c = 0; c < C2; ++c) Acol[c] = A[c * C2 + lane];

    int jvv[12];
    #pragma unroll
    for (int t = 0; t < 12; ++t) jvv[t] = __shfl(myCand, hf * 12 + t, 64);
    float pscv[12];
    #pragma unroll
    for (int t = 0; t < 12; ++t) pscv[t] = psb[(long)jvv[t] * C2 + lane];

    #pragma unroll 1
    for (int tt = 0; tt < 12; tt += 2) {
        const int t = hf * 12 + tt;
        float e0 = expf(pscv[tt]     - pm_own);
        float e1 = expf(pscv[tt + 1] - pm_own);
        float sA = 1.0f / __fadd_rn(1.0f, e0);       // sigmoid(pm-ps), lane=c
        float sB = 1.0f / __fadd_rn(1.0f, e1);
        sC[wv8][0][lane] = sA;
        sC[wv8][1][lane] = sB;
        LDS_FENCE();
        float wd0 = 0.f, wd1 = 0.f;
        #pragma unroll
        for (int c = 0; c < C2; ++c) {               // ascending c, single acc each
            wd0 = fmaf(sC[wv8][0][c], Acol[c], wd0);
            wd1 = fmaf(sC[wv8][1][c], Acol[c], wd1);
        }
        const float t0 = __fmul_rn(wd0, sA);         // t_d = w_d * s_d, lane=d
        const float t1 = __fmul_rn(wd1, sB);
        // numpy pairwise-8 via shfl (same op order as np), both candidates
        float r80 = t0, r81 = t1;
        #pragma unroll
        for (int blk = 1; blk < 8; ++blk) {
            r80 = __fadd_rn(r80, __shfl(t0, (lane & 7) + 8 * blk, 64));
            r81 = __fadd_rn(r81, __shfl(t1, (lane & 7) + 8 * blk, 64));
        }
        float dis2a = __fadd_rn(
            __fadd_rn(__fadd_rn(__shfl(r80, 0, 64), __shfl(r80, 1, 64)),
                      __fadd_rn(__shfl(r80, 2, 64), __shfl(r80, 3, 64))),
            __fadd_rn(__fadd_rn(__shfl(r80, 4, 64), __shfl(r80, 5, 64)),
                      __fadd_rn(__shfl(r80, 6, 64), __shfl(r80, 7, 64))));
        float dis2b = __fadd_rn(
            __fadd_rn(__fadd_rn(__shfl(r81, 0, 64), __shfl(r81, 1, 64)),
                      __fadd_rn(__shfl(r81, 2, 64), __shfl(r81, 3, 64))),
            __fadd_rn(__fadd_rn(__shfl(r81, 4, 64), __shfl(r81, 5, 64)),
                      __fadd_rn(__shfl(r81, 6, 64), __shfl(r81, 7, 64))));
        float cda = 1.0f / __fadd_rn(1.0f, expf(sqrtf(dis2a)));  // sigmoid(-dis)
        float cdb = 1.0f / __fadd_rn(1.0f, expf(sqrtf(dis2b)));
        if (lane == 0) {
            cdiffL[qt][t]     = cda;
            cdiffL[qt][t + 1] = cdb;
        }
    }
    __syncthreads();

    // ---- Final: hf==0 waves: top-16 over NCAND exact diffs ----
    if (hf == 0) {
        float myd = (lane < NCAND) ? cdiffL[qt][lane] : -2.0f;
        int myj = (lane < NCAND) ? myCand : (1 << 20);

        const int obase = b * (NN * KK) + i * KK;    // index chunk (f32)
        const int vbase = 2 * NN * KK + obase;       // value chunk (f32)

        #pragma unroll 1
        for (int k = 0; k < KK; ++k) {
            float bd = myd;
            int bj = myj;
            #pragma unroll
            for (int st = 0; st < 6; ++st) {
                int msk = 1 << st;
                float od = __shfl_xor(bd, msk, 64);
                int oj = __shfl_xor(bj, msk, 64);
                bool better = (od > bd) || (od == bd && oj < bj);
                bd = better ? od : bd;
                bj = better ? oj : bj;
            }
            if (myj == bj) myd = -2.0f;              // candidate j's unique
            if (lane == 0) {
                out[obase + k] = (float)bj;
                out[vbase + k] = -bd;                // value = -topk(diff)
            }
        }
    }
}

extern "C" void kernel_launch(void* const* d_in, const int* in_sizes, int n_in,
                              void* d_out, int out_size, void* d_ws, size_t ws_size,
                              hipStream_t stream) {
    const float* X  = (const float*)d_in[0];
    const float* Wm = (const float*)d_in[1];
    const float* Ws = (const float*)d_in[2];
    const float* M  = (const float*)d_in[3];

    float* A   = (float*)d_ws;           // 4096 f   (16 KB)
    float* pm  = A + C2 * C2;            // 131072 f (512 KB)
    float* ps  = pm + 2 * NN * C2;       // 131072 f (512 KB)
    float* psE = ps + 2 * NN * C2;       // 131072 f (512 KB)  total ~1.52 MB
    float* out = (float*)d_out;          // f32: [idx 32768][val 32768]

    hipLaunchKernelGGL(proj_buildA, dim3(2 * NN + 32), dim3(128), 0, stream,
                       X, Wm, Ws, M, pm, ps, psE, A);
    hipLaunchKernelGGL(pair_topk, dim3(512), dim3(512), 0, stream,
                       pm, ps, psE, M, A, out);
}

// Round 25
// 88.552 us; speedup vs baseline: 1.2230x; 1.2230x over previous
//
#include <hip/hip_runtime.h>
#include <hip/hip_bf16.h>
#include <hip/hip_fp16.h>
#include <math.h>

#define NN 1024
#define CC 128
#define C2 64
#define KK 16
#define NCAND 24

#if __has_builtin(__builtin_amdgcn_exp2f)
#define EXP2F(x) __builtin_amdgcn_exp2f(x)
#else
#define EXP2F(x) exp2f(x)
#endif
#define LOG2E 1.4426950408889634f

typedef __fp16  hf2   __attribute__((ext_vector_type(2)));   // cvt_pkrtz result type
typedef _Float16 half8 __attribute__((ext_vector_type(8)));  // MFMA operand type
typedef float f32x4    __attribute__((ext_vector_type(4)));
typedef int   int4v    __attribute__((ext_vector_type(4)));
typedef unsigned int uint;

__device__ __forceinline__ float fast_rcp(float x) {
    return __builtin_amdgcn_rcpf(x);
}

// In-wave LDS write->read visibility: wait LDS ops, pin compiler order.
#define LDS_FENCE() do { \
    asm volatile("s_waitcnt lgkmcnt(0)" ::: "memory"); \
    __builtin_amdgcn_sched_barrier(0); } while (0)

// ---------------- K1: proj (np-exact) + psE, fused with buildA -------------
// blocks [0, 2*NN): proj; blocks [2*NN, 2*NN+32): A = M^T M.
__global__ __launch_bounds__(128) void proj_buildA(
        const float* __restrict__ X,
        const float* __restrict__ Wm,
        const float* __restrict__ Ws,
        const float* __restrict__ M,
        float* __restrict__ pm,
        float* __restrict__ ps,
        float* __restrict__ psE,
        float* __restrict__ A) {
    if (blockIdx.x >= 2 * NN) {          // ---- buildA: 32 blocks x 128 thr
        const int e = (blockIdx.x - 2 * NN) * 128 + threadIdx.x;  // < 4096
        const int c = e >> 6, d = e & 63;
        float acc = 0.f;
        #pragma unroll 8
        for (int r = 0; r < C2; ++r)
            acc = fmaf(M[r * C2 + c], M[r * C2 + d], acc);
        A[e] = acc;                      // A[c][d] row-major
        return;
    }

    const int bn = blockIdx.x;           // b*1024 + n
    const int b  = bn >> 10;
    const int n  = bn & (NN - 1);
    const int t  = threadIdx.x;          // 0..127

    __shared__ float xv[CC];
    xv[t] = X[b * CC * NN + t * NN + n];
    __syncthreads();

    const int d = t & (C2 - 1);
    const float* wr = ((t < C2) ? Wm : Ws) + d * CC;
    float acc = 0.f;
    #pragma unroll
    for (int c = 0; c < CC; ++c)
        acc = fmaf(wr[c], xv[c], acc);   // sequential k-order, single acc

    float a = __fadd_rn(fabsf(acc), 1e-10f);
    float l = logf(a);
    float r = (acc > 0.f) ? l : ((acc < 0.f) ? -l : 0.f);
    if (t < C2) {
        pm[bn * C2 + d] = r;
    } else {
        ps[bn * C2 + d] = r;
        psE[bn * C2 + d] = EXP2F(r * LOG2E);   // e^ps (proxy pass only)
    }
}

// f32 sigmoid -> packed fp16 B-fragment (single term; proxy only).
#define SIGF16(PMEF, Y0, Y1, BF) do {                                         \
    float s0 = PMEF[0] * fast_rcp(PMEF[0] + (Y0).x);                          \
    float s1 = PMEF[1] * fast_rcp(PMEF[1] + (Y0).y);                          \
    float s2 = PMEF[2] * fast_rcp(PMEF[2] + (Y0).z);                          \
    float s3 = PMEF[3] * fast_rcp(PMEF[3] + (Y0).w);                          \
    float s4 = PMEF[4] * fast_rcp(PMEF[4] + (Y1).x);                          \
    float s5 = PMEF[5] * fast_rcp(PMEF[5] + (Y1).y);                          \
    float s6 = PMEF[6] * fast_rcp(PMEF[6] + (Y1).z);                          \
    float s7 = PMEF[7] * fast_rcp(PMEF[7] + (Y1).w);                          \
    hf2 p0 = __builtin_amdgcn_cvt_pkrtz(s0, s1);                              \
    hf2 p1 = __builtin_amdgcn_cvt_pkrtz(s2, s3);                              \
    hf2 p2 = __builtin_amdgcn_cvt_pkrtz(s4, s5);                              \
    hf2 p3 = __builtin_amdgcn_cvt_pkrtz(s6, s7);                              \
    int4v iv = { __builtin_bit_cast(int, p0), __builtin_bit_cast(int, p1),    \
                 __builtin_bit_cast(int, p2), __builtin_bit_cast(int, p3) };  \
    BF = __builtin_bit_cast(half8, iv);                                       \
} while (0)

// SINGLE-term fp16 A: 4 MFMA per kt-fragment.
// fp16(M) RNE error adds ~1.6e-3 to du (~2.5 abs on dis2) vs rank gap ~15.
#define MFMA4(AC, KT, B)                                                              \
    AC[0] = __builtin_amdgcn_mfma_f32_16x16x32_f16(af[0][KT], B, AC[0], 0, 0, 0);     \
    AC[1] = __builtin_amdgcn_mfma_f32_16x16x32_f16(af[1][KT], B, AC[1], 0, 0, 0);     \
    AC[2] = __builtin_amdgcn_mfma_f32_16x16x32_f16(af[2][KT], B, AC[2], 0, 0, 0);     \
    AC[3] = __builtin_amdgcn_mfma_f32_16x16x32_f16(af[3][KT], B, AC[3], 0, 0, 0);

// One stream: build 2 fp16 B-fragments, 8 MFMA
#define STREAM(PMEF, T0, T1, T2, T3, AC) do {                                 \
    half8 b0, b1;                                                             \
    SIGF16(PMEF[0], T0, T1, b0);                                              \
    SIGF16(PMEF[1], T2, T3, b1);                                              \
    MFMA4(AC, 0, b0)                                                          \
    MFMA4(AC, 1, b1)                                                          \
} while (0)

#define SQUARE16(AC, S) do {                                                  \
    _Pragma("unroll")                                                         \
    for (int e = 0; e < 4; ++e) {                                             \
        S = fmaf(AC[0][e], AC[0][e], S);                                      \
        S = fmaf(AC[1][e], AC[1][e], S);                                      \
        S = fmaf(AC[2][e], AC[2][e], S);                                      \
        S = fmaf(AC[3][e], AC[3][e], S);                                      \
    }                                                                         \
} while (0)

// ---------------- K2: 4 rows per wave x quarter-j, 512 blocks --------------
// Block = 4 waves = 4 rows. Wave wv covers j-tiles [wv*16, wv*16+16) for ALL
// 4 block rows: ONE psE tile load feeds 4 rows' sigmoid+MFMA streams (psE
// read once per block, 4x compute per load). d2u[r][j]: wave writes its
// quarter for each local row r. Barrier. Phases B/C/F: wave wv owns local
// row wv (np-exact phase C, 2-candidate interleaved).
// NOTE (R22-R24 post-mortems): deferred-reduce pipelining, 8-wave split, and
// forced-occupancy variants ALL regressed -- this structure is the empirical
// optimum; 2 waves/SIMD saturates the shared VALU/transcendental paths.
__global__ __launch_bounds__(256, 2) void pair_topk(
        const float* __restrict__ pm,
        const float* __restrict__ ps,
        const float* __restrict__ psE,
        const float* __restrict__ Mf,
        const float* __restrict__ A,
        float* __restrict__ out) {
    const int tid  = threadIdx.x;
    const int wv   = tid >> 6;           // 0..3 (j-quarter in phase A; row in B/C/F)
    const int lane = tid & 63;
    const int g    = lane >> 4;          // k-group 0..3
    const int lj   = lane & 15;          // col (B) / row (A) within tile

    const int rbase = blockIdx.x * 4;    // first row of block (b-uniform)
    const int b     = rbase >> 10;

    __shared__ uint  d2u[4][NN];         // packed (d2 & ~0x3FF) | j  (16 KB)
    __shared__ float sC[4][2][C2];
    __shared__ float cdiffL[4][NCAND];

    const float* psb  = ps  + b * NN * C2;
    const float* psEb = psE + b * NN * C2;

    // ---- Phase A: 4 rows over this wave's j-quarter, 1 tile/iter ----
    {
        float pmEf[4][2][8];             // e^pm fragments, all 4 block rows
        #pragma unroll
        for (int r = 0; r < 4; ++r) {
            #pragma unroll
            for (int kt = 0; kt < 2; ++kt) {
                const float4 a0 = *(const float4*)(pm + (rbase + r) * C2 + kt * 32 + g * 8);
                const float4 a1 = *(const float4*)(pm + (rbase + r) * C2 + kt * 32 + g * 8 + 4);
                pmEf[r][kt][0] = EXP2F(a0.x * LOG2E); pmEf[r][kt][1] = EXP2F(a0.y * LOG2E);
                pmEf[r][kt][2] = EXP2F(a0.z * LOG2E); pmEf[r][kt][3] = EXP2F(a0.w * LOG2E);
                pmEf[r][kt][4] = EXP2F(a1.x * LOG2E); pmEf[r][kt][5] = EXP2F(a1.y * LOG2E);
                pmEf[r][kt][6] = EXP2F(a1.z * LOG2E); pmEf[r][kt][7] = EXP2F(a1.w * LOG2E);
            }
        }

        half8 af[4][2];                  // M rows single fp16 (RNE, once)
        #pragma unroll
        for (int rt = 0; rt < 4; ++rt) {
            #pragma unroll
            for (int kt = 0; kt < 2; ++kt) {
                const float* mrow = Mf + (rt * 16 + lj) * C2 + kt * 32 + g * 8;
                const float4 m0 = *(const float4*)mrow;
                const float4 m1 = *(const float4*)(mrow + 4);
                float mv[8] = {m0.x, m0.y, m0.z, m0.w, m1.x, m1.y, m1.z, m1.w};
                #pragma unroll
                for (int e = 0; e < 8; ++e)
                    af[rt][kt][e] = (_Float16)mv[e];        // RNE f32->f16
            }
        }

        const int tbase = wv * 16;       // this wave's 16 tiles
        const float* p0 = psEb + (long)((tbase + 0) * 16 + lj) * C2 + g * 8;
        float4 c0 = *(const float4*)(p0);      float4 c1 = *(const float4*)(p0 + 4);
        float4 c2 = *(const float4*)(p0 + 32); float4 c3 = *(const float4*)(p0 + 36);

        #pragma unroll 1
        for (int it = 0; it < 16; ++it) {
            float4 n0, n1, n2, n3;
            if (it < 15) {                       // issue next-tile loads EARLY
                const float* q0 = psEb + (long)((tbase + it + 1) * 16 + lj) * C2 + g * 8;
                n0 = *(const float4*)(q0);      n1 = *(const float4*)(q0 + 4);
                n2 = *(const float4*)(q0 + 32); n3 = *(const float4*)(q0 + 36);
            }

            f32x4 ac0[4] = {{0,0,0,0},{0,0,0,0},{0,0,0,0},{0,0,0,0}};
            f32x4 ac1[4] = {{0,0,0,0},{0,0,0,0},{0,0,0,0},{0,0,0,0}};
            f32x4 ac2[4] = {{0,0,0,0},{0,0,0,0},{0,0,0,0},{0,0,0,0}};
            f32x4 ac3[4] = {{0,0,0,0},{0,0,0,0},{0,0,0,0},{0,0,0,0}};

            __builtin_amdgcn_s_setprio(1);
            STREAM(pmEf[0], c0, c1, c2, c3, ac0);
            STREAM(pmEf[1], c0, c1, c2, c3, ac1);
            STREAM(pmEf[2], c0, c1, c2, c3, ac2);
            STREAM(pmEf[3], c0, c1, c2, c3, ac3);
            __builtin_amdgcn_s_setprio(0);

            float s0 = 0.f, s1 = 0.f, s2 = 0.f, s3 = 0.f;
            SQUARE16(ac0, s0);
            SQUARE16(ac1, s1);
            SQUARE16(ac2, s2);
            SQUARE16(ac3, s3);
            s0 += __shfl_xor(s0, 16, 64); s0 += __shfl_xor(s0, 32, 64);
            s1 += __shfl_xor(s1, 16, 64); s1 += __shfl_xor(s1, 32, 64);
            s2 += __shfl_xor(s2, 16, 64); s2 += __shfl_xor(s2, 32, 64);
            s3 += __shfl_xor(s3, 16, 64); s3 += __shfl_xor(s3, 32, 64);
            if (lane < 16) {
                const int jj = (tbase + it) * 16 + lane;
                d2u[0][jj] = (__float_as_uint(s0) & 0xFFFFFC00u) | (uint)jj;
                d2u[1][jj] = (__float_as_uint(s1) & 0xFFFFFC00u) | (uint)jj;
                d2u[2][jj] = (__float_as_uint(s2) & 0xFFFFFC00u) | (uint)jj;
                d2u[3][jj] = (__float_as_uint(s3) & 0xFFFFFC00u) | (uint)jj;
            }

            c0 = n0; c1 = n1; c2 = n2; c3 = n3;
        }
    }
    __syncthreads();

    // ---- Phases B/C/F: wave wv owns row rbase+wv ----
    const int bi = rbase + wv;
    const int i  = bi & (NN - 1);
    const float pm_own = pm[bi * C2 + lane];

    // Phase B: top-NCAND via packed-uint min passes
    uint v[16];
    #pragma unroll
    for (int q = 0; q < 16; ++q) v[q] = d2u[wv][q * 64 + lane];

    int myCand = 0;
    #pragma unroll 1
    for (int k = 0; k < NCAND; ++k) {
        uint bv = v[0];
        #pragma unroll
        for (int q = 1; q < 16; ++q) bv = min(bv, v[q]);
        #pragma unroll
        for (int st = 0; st < 6; ++st)
            bv = min(bv, (uint)__shfl_xor((int)bv, 1 << st, 64));
        #pragma unroll
        for (int q = 0; q < 16; ++q)
            if (v[q] == bv) v[q] = 0xFFFFFFFFu;
        if (lane == k) myCand = (int)(bv & 0x3FFu);
    }

    // Phase C: np-exact rescore (R6 bit-exact op order per candidate),
    // TWO candidates in flight (independent serial chains -> 2x latency hide)
    float Acol[C2];
    #pragma unroll
    for (int c = 0; c < C2; ++c) Acol[c] = A[c * C2 + lane];

    int jvv[NCAND];
    #pragma unroll
    for (int t = 0; t < NCAND; ++t) jvv[t] = __shfl(myCand, t, 64);
    float pscv[NCAND];
    #pragma unroll
    for (int t = 0; t < NCAND; ++t) pscv[t] = psb[(long)jvv[t] * C2 + lane];

    #pragma unroll 1
    for (int t = 0; t < NCAND; t += 2) {
        float e0 = expf(pscv[t]     - pm_own);
        float e1 = expf(pscv[t + 1] - pm_own);
        float sA = 1.0f / __fadd_rn(1.0f, e0);       // sigmoid(pm-ps), lane=c
        float sB = 1.0f / __fadd_rn(1.0f, e1);
        sC[wv][0][lane] = sA;
        sC[wv][1][lane] = sB;
        LDS_FENCE();
        float wd0 = 0.f, wd1 = 0.f;
        #pragma unroll
        for (int c = 0; c < C2; ++c) {               // ascending c, single acc each
            wd0 = fmaf(sC[wv][0][c], Acol[c], wd0);
            wd1 = fmaf(sC[wv][1][c], Acol[c], wd1);
        }
        const float t0 = __fmul_rn(wd0, sA);         // t_d = w_d * s_d, lane=d
        const float t1 = __fmul_rn(wd1, sB);
        // numpy pairwise-8 via shfl (same op order as np), both candidates
        float r80 = t0, r81 = t1;
        #pragma unroll
        for (int blk = 1; blk < 8; ++blk) {
            r80 = __fadd_rn(r80, __shfl(t0, (lane & 7) + 8 * blk, 64));
            r81 = __fadd_rn(r81, __shfl(t1, (lane & 7) + 8 * blk, 64));
        }
        float dis2a = __fadd_rn(
            __fadd_rn(__fadd_rn(__shfl(r80, 0, 64), __shfl(r80, 1, 64)),
                      __fadd_rn(__shfl(r80, 2, 64), __shfl(r80, 3, 64))),
            __fadd_rn(__fadd_rn(__shfl(r80, 4, 64), __shfl(r80, 5, 64)),
                      __fadd_rn(__shfl(r80, 6, 64), __shfl(r80, 7, 64))));
        float dis2b = __fadd_rn(
            __fadd_rn(__fadd_rn(__shfl(r81, 0, 64), __shfl(r81, 1, 64)),
                      __fadd_rn(__shfl(r81, 2, 64), __shfl(r81, 3, 64))),
            __fadd_rn(__fadd_rn(__shfl(r81, 4, 64), __shfl(r81, 5, 64)),
                      __fadd_rn(__shfl(r81, 6, 64), __shfl(r81, 7, 64))));
        float cda = 1.0f / __fadd_rn(1.0f, expf(sqrtf(dis2a)));  // sigmoid(-dis)
        float cdb = 1.0f / __fadd_rn(1.0f, expf(sqrtf(dis2b)));
        if (lane == 0) {
            cdiffL[wv][t]     = cda;
            cdiffL[wv][t + 1] = cdb;
        }
    }
    LDS_FENCE();

    // Final: per-wave top-16 over NCAND exact diffs (desc, index asc)
    float myd = (lane < NCAND) ? cdiffL[wv][lane] : -2.0f;
    int myj = (lane < NCAND) ? myCand : (1 << 20);

    const int obase = b * (NN * KK) + i * KK;        // index chunk (f32)
    const int vbase = 2 * NN * KK + obase;           // value chunk (f32)

    #pragma unroll 1
    for (int k = 0; k < KK; ++k) {
        float bd = myd;
        int bj = myj;
        #pragma unroll
        for (int st = 0; st < 6; ++st) {
            int msk = 1 << st;
            float od = __shfl_xor(bd, msk, 64);
            int oj = __shfl_xor(bj, msk, 64);
            bool better = (od > bd) || (od == bd && oj < bj);
            bd = better ? od : bd;
            bj = better ? oj : bj;
        }
        if (myj == bj) myd = -2.0f;                  // candidate j's unique
        if (lane == 0) {
            out[obase + k] = (float)bj;
            out[vbase + k] = -bd;                    // value = -topk(diff)
        }
    }
}

extern "C" void kernel_launch(void* const* d_in, const int* in_sizes, int n_in,
                              void* d_out, int out_size, void* d_ws, size_t ws_size,
                              hipStream_t stream) {
    const float* X  = (const float*)d_in[0];
    const float* Wm = (const float*)d_in[1];
    const float* Ws = (const float*)d_in[2];
    const float* M  = (const float*)d_in[3];

    float* A   = (float*)d_ws;           // 4096 f   (16 KB)
    float* pm  = A + C2 * C2;            // 131072 f (512 KB)
    float* ps  = pm + 2 * NN * C2;       // 131072 f (512 KB)
    float* psE = ps + 2 * NN * C2;       // 131072 f (512 KB)  total ~1.52 MB
    float* out = (float*)d_out;          // f32: [idx 32768][val 32768]

    hipLaunchKernelGGL(proj_buildA, dim3(2 * NN + 32), dim3(128), 0, stream,
                       X, Wm, Ws, M, pm, ps, psE, A);
    hipLaunchKernelGGL(pair_topk, dim3(512), dim3(256), 0, stream,
                       pm, ps, psE, M, A, out);
}